// Round 13
// baseline (143.959 us; speedup 1.0000x reference)
//
#include <hip/hip_runtime.h>

typedef float f4 __attribute__((ext_vector_type(4)));
typedef float f2 __attribute__((ext_vector_type(2)));

#define NPIX (32*512*512)        // 8388608
#define BN_EPS 1e-5f

// ws float layout (memset clears first 2048 bytes = floats 0..511):
// [0..5]    M1 sums of s_i
// [6..26]   M2 sums (upper tri, idx = 6 + a*(11-a)/2 + b, a<=b)
// [27]      S1 (sum o_pre), [28] S2 (sum o_pre^2)
// [32..256) wpack[28][8] = {w0,w1,w2,w3,w4,w5,beff,w2c}; ch 25..27 stay zero
// [496]     zbuf (zero region; loadrows touches floats 495..500)

struct Rows { f4 C, N, S; float wv, ev, nwv, sev; };

__device__ __forceinline__ Rows loadrows(const float* __restrict__ x,
                                         const float* zbuf, int p) {
    Rows r;
    int rem = p & (512*512 - 1);
    int i = rem >> 9, jj = rem & 511;          // jj multiple of 4
    const float* xc = x + p;
    const float* xn = (i > 0)   ? xc - 512 : zbuf;
    const float* xs = (i < 511) ? xc + 512 : zbuf;
    r.C = *(const f4*)xc;
    r.N = *(const f4*)xn;
    r.S = *(const f4*)xs;
    bool hw = (jj > 0), he = (jj < 508);
    float wv  = xc[hw ? -1 : 0];
    float ev  = xc[he ?  4 : 3];
    float nwv = xn[hw ? -1 : 0];
    float sev = xs[he ?  4 : 3];
    r.wv  = hw ? wv  : 0.f;
    r.ev  = he ? ev  : 0.f;
    r.nwv = hw ? nwv : 0.f;
    r.sev = he ? sev : 0.f;
    return r;
}

__device__ __forceinline__ void mkstencil(const Rows& r, f4* s) {
    f4 E   = {r.C.y, r.C.z, r.C.w, r.ev};
    f4 W   = {r.wv,  r.C.x, r.C.y, r.C.z};
    f4 Ssh = {r.S.y, r.S.z, r.S.w, r.sev};
    f4 Nsh = {r.nwv, r.N.x, r.N.y, r.N.z};
    s[0] = r.C;
    s[1] = (r.S - r.N) * 0.5f;
    s[2] = (E - W) * 0.5f;
    s[3] = r.S + r.N - 2.f*r.C;
    s[4] = E + W - 2.f*r.C;
    s[5] = Ssh + Nsh - r.S - E;
}

// ---------------- k_moments: 16 px/thread, packed f2 accumulators ----------------
__global__ __launch_bounds__(256) void k_moments(const float* __restrict__ x,
                                                 float* ws) {
    const float* zbuf = ws + 496;
    int t = threadIdx.x;
    int g0 = blockIdx.x * 1024 + t;            // first f4-group of this thread
    f2 acc[27];
    #pragma unroll
    for (int i = 0; i < 27; ++i) acc[i] = (f2){0.f, 0.f};

    #pragma unroll
    for (int q = 0; q < 4; ++q) {
        Rows r = loadrows(x, zbuf, (g0 + 256*q) * 4);
        f4 s[6];
        mkstencil(r, s);
        #pragma unroll
        for (int a = 0; a < 6; ++a) {
            f2 alo = s[a].xy, ahi = s[a].zw;
            asm("v_pk_add_f32 %0, %1, %0" : "+v"(acc[a]) : "v"(alo));
            asm("v_pk_add_f32 %0, %1, %0" : "+v"(acc[a]) : "v"(ahi));
            #pragma unroll
            for (int b = a; b < 6; ++b) {
                int idx = 6 + a*(11-a)/2 + b;
                f2 blo = s[b].xy, bhi = s[b].zw;
                asm("v_pk_fma_f32 %0, %1, %2, %0" : "+v"(acc[idx]) : "v"(alo), "v"(blo));
                asm("v_pk_fma_f32 %0, %1, %2, %0" : "+v"(acc[idx]) : "v"(ahi), "v"(bhi));
            }
        }
    }
    __shared__ float red[27][4];
    int wave = t >> 6, lane = t & 63;
    #pragma unroll
    for (int i = 0; i < 27; ++i) {
        float v = acc[i].x + acc[i].y;
        for (int off = 32; off; off >>= 1) v += __shfl_xor(v, off);
        if (lane == 0) red[i][wave] = v;
    }
    __syncthreads();
    if (t < 27) atomicAdd(&ws[t], red[t][0] + red[t][1] + red[t][2] + red[t][3]);
}

__global__ void k_stats1(const float* w1, const float* b1, const float* g1,
                         const float* beta1, const float* w2, float* ws) {
    int c = threadIdx.x;
    if (c >= 25) return;
    const float invN = 1.f / (float)NPIX;
    float m1[6], wr[6];
    #pragma unroll
    for (int i = 0; i < 6; ++i) m1[i] = ws[i] * invN;
    #pragma unroll
    for (int i = 0; i < 6; ++i) wr[i] = w1[c*6 + i];
    float bc = b1[c];
    float mean = bc;
    #pragma unroll
    for (int i = 0; i < 6; ++i) mean = fmaf(wr[i], m1[i], mean);
    float e2 = bc * bc;
    #pragma unroll
    for (int i = 0; i < 6; ++i) e2 = fmaf(2.f*bc*wr[i], m1[i], e2);
    #pragma unroll
    for (int i = 0; i < 6; ++i)
        #pragma unroll
        for (int j = 0; j < 6; ++j) {
            int a = i < j ? i : j, b = i < j ? j : i;
            float m2 = ws[6 + a*(11-a)/2 + b] * invN;
            e2 = fmaf(wr[i]*wr[j], m2, e2);
        }
    float var = e2 - mean*mean;
    float a1 = g1[c] * rsqrtf(var + BN_EPS);
    float* wp = ws + 32 + c*8;
    #pragma unroll
    for (int i = 0; i < 6; ++i) wp[i] = a1 * wr[i];
    wp[6] = fmaf(a1, bc - mean, beta1[c]);   // beff
    wp[7] = w2[c];                           // w2c
}

// -------- k_main: 16 px/thread, pk conv w/ op_sel bcast, 4 SGPR groups x 7 ch --------
__global__ __launch_bounds__(256) void k_main(const float* __restrict__ x,
                                              const float* __restrict__ wts,
                                              const float* __restrict__ zbuf,
                                              const float* __restrict__ b2,
                                              float* __restrict__ stats,
                                              float* __restrict__ opre) {
    int t = threadIdx.x;
    int g0 = blockIdx.x * 1024 + t;            // first f4-group of this thread

    f4 s[4][6];
    #pragma unroll
    for (int q = 0; q < 4; ++q) {
        Rows r = loadrows(x, zbuf, (g0 + 256*q) * 4);
        mkstencil(r, s[q]);
    }

    float b2v = b2[0];
    f2 o2[4][2];
    #pragma unroll
    for (int q = 0; q < 4; ++q) {
        o2[q][0] = (f2){b2v, b2v};
        o2[q][1] = (f2){b2v, b2v};
    }

    // 4 groups of 7 channels; 56 weight floats/group resident in SGPRs (R11-proven).
    #pragma unroll 1
    for (int g = 0; g < 4; ++g) {
        const f2* wg = (const f2*)(wts + g * 56);
        #pragma unroll
        for (int c = 0; c < 7; ++c) {
            f2 W01 = wg[c*4+0];   // {w0,w1}
            f2 W23 = wg[c*4+1];   // {w2,w3}
            f2 W45 = wg[c*4+2];   // {w4,w5}
            f2 BW  = wg[c*4+3];   // {beff,w2c}
            #pragma unroll
            for (int q = 0; q < 4; ++q) {
                #pragma unroll
                for (int h = 0; h < 2; ++h) {
                    f2 sp0 = h ? s[q][0].zw : s[q][0].xy;
                    f2 sp1 = h ? s[q][1].zw : s[q][1].xy;
                    f2 sp2 = h ? s[q][2].zw : s[q][2].xy;
                    f2 sp3 = h ? s[q][3].zw : s[q][3].xy;
                    f2 sp4 = h ? s[q][4].zw : s[q][4].xy;
                    f2 sp5 = h ? s[q][5].zw : s[q][5].xy;
                    f2 tt;
                    asm("v_pk_mul_f32 %0, %1, %2 op_sel:[0,0] op_sel_hi:[0,1]"
                        : "=v"(tt) : "s"(W01), "v"(sp0));            // w0*sp0
                    asm("v_pk_fma_f32 %0, %1, %2, %0 op_sel:[1,0,0] op_sel_hi:[1,1,1]"
                        : "+v"(tt) : "s"(W01), "v"(sp1));            // +w1*sp1
                    asm("v_pk_fma_f32 %0, %1, %2, %0 op_sel:[0,0,0] op_sel_hi:[0,1,1]"
                        : "+v"(tt) : "s"(W23), "v"(sp2));            // +w2*sp2
                    asm("v_pk_fma_f32 %0, %1, %2, %0 op_sel:[1,0,0] op_sel_hi:[1,1,1]"
                        : "+v"(tt) : "s"(W23), "v"(sp3));            // +w3*sp3
                    asm("v_pk_fma_f32 %0, %1, %2, %0 op_sel:[0,0,0] op_sel_hi:[0,1,1]"
                        : "+v"(tt) : "s"(W45), "v"(sp4));            // +w4*sp4
                    asm("v_pk_fma_f32 %0, %1, %2, %0 op_sel:[1,0,0] op_sel_hi:[1,1,1]"
                        : "+v"(tt) : "s"(W45), "v"(sp5));            // +w5*sp5
                    asm("v_pk_add_f32 %0, %1, %0 op_sel:[0,0] op_sel_hi:[0,1]"
                        : "+v"(tt) : "s"(BW));                       // +beff
                    tt.x = fmaxf(tt.x, 0.f);
                    tt.y = fmaxf(tt.y, 0.f);
                    asm("v_pk_fma_f32 %0, %1, %2, %0 op_sel:[1,0,0] op_sel_hi:[1,1,1]"
                        : "+v"(o2[q][h]) : "s"(BW), "v"(tt));        // o += w2c*relu
                }
            }
        }
    }

    float l1 = 0.f, l2 = 0.f;
    #pragma unroll
    for (int q = 0; q < 4; ++q) {
        f4 O = {o2[q][0].x, o2[q][0].y, o2[q][1].x, o2[q][1].y};
        *(f4*)(opre + (g0 + 256*q) * 4) = O;
        l1 += (O.x + O.y) + (O.z + O.w);
        l2 = fmaf(O.x, O.x, l2); l2 = fmaf(O.y, O.y, l2);
        l2 = fmaf(O.z, O.z, l2); l2 = fmaf(O.w, O.w, l2);
    }
    for (int off = 32; off; off >>= 1) { l1 += __shfl_xor(l1, off); l2 += __shfl_xor(l2, off); }
    __shared__ float red[2][4];
    int wave = t >> 6, lane = t & 63;
    if (lane == 0) { red[0][wave] = l1; red[1][wave] = l2; }
    __syncthreads();
    if (t == 0) atomicAdd(&stats[27], red[0][0]+red[0][1]+red[0][2]+red[0][3]);
    if (t == 1) atomicAdd(&stats[28], red[1][0]+red[1][1]+red[1][2]+red[1][3]);
}

// ---------------- k_final: BN2 fold computed inline (stats2 fused) ----------------
__global__ __launch_bounds__(256) void k_final(const float* __restrict__ x,
                                               const float* __restrict__ ws,
                                               const float* __restrict__ g2,
                                               const float* __restrict__ beta2,
                                               float* __restrict__ out) {
    const float invN = 1.f / (float)NPIX;
    float mean = ws[27] * invN;
    float var  = ws[28] * invN - mean*mean;
    float a2 = g2[0] * rsqrtf(var + BN_EPS);
    float c2 = fmaf(-mean, a2, beta2[0]);

    int idx = blockIdx.x * 256 + threadIdx.x;  // f4 index, 8192 blocks
    f4 o  = ((const f4*)out)[idx];
    f4 xv = ((const f4*)x)[idx];
    f4 r;
    r.x = fmaxf(fmaf(a2, o.x, c2), 0.f) + xv.x;
    r.y = fmaxf(fmaf(a2, o.y, c2), 0.f) + xv.y;
    r.z = fmaxf(fmaf(a2, o.z, c2), 0.f) + xv.z;
    r.w = fmaxf(fmaf(a2, o.w, c2), 0.f) + xv.w;
    ((f4*)out)[idx] = r;
}

extern "C" void kernel_launch(void* const* d_in, const int* in_sizes, int n_in,
                              void* d_out, int out_size, void* d_ws, size_t ws_size,
                              hipStream_t stream) {
    const float* x     = (const float*)d_in[0];
    const float* w1    = (const float*)d_in[1];
    const float* b1    = (const float*)d_in[2];
    const float* g1    = (const float*)d_in[3];
    const float* beta1 = (const float*)d_in[4];
    const float* w2    = (const float*)d_in[5];
    const float* b2    = (const float*)d_in[6];
    const float* g2    = (const float*)d_in[7];
    const float* beta2 = (const float*)d_in[8];
    float* out = (float*)d_out;
    float* ws  = (float*)d_ws;

    hipMemsetAsync(ws, 0, 2048, stream);
    k_moments<<<2048, 256, 0, stream>>>(x, ws);
    k_stats1 <<<1, 32, 0, stream>>>(w1, b1, g1, beta1, w2, ws);
    k_main   <<<2048, 256, 0, stream>>>(x, ws + 32, ws + 496, b2, ws, out);
    k_final  <<<8192, 256, 0, stream>>>(x, ws, g2, beta2, out);
}

// Round 14
// 134.838 us; speedup vs baseline: 1.0676x; 1.0676x over previous
//
#include <hip/hip_runtime.h>
#include <hip/hip_fp16.h>

typedef float f4 __attribute__((ext_vector_type(4)));
typedef float f2 __attribute__((ext_vector_type(2)));
typedef _Float16 f16x8 __attribute__((ext_vector_type(8)));
typedef float f32x16 __attribute__((ext_vector_type(16)));

#define NPIX (32*512*512)        // 8388608
#define BN_EPS 1e-5f

// ws float layout (memset clears first 2048 bytes = floats 0..511):
// [0..26]   M1/M2 moment sums
// [27] S1, [28] S2
// [64..95]  w2pad[32] (zero-padded w2)
// [96..352) A-fragment per lane: 64 x 4 uints (f16x8 bit patterns)
// [496..]   zbuf (zero region; reads touch floats 495..500)

struct Rows { f4 C, N, S; float wv, ev, nwv, sev; };

__device__ __forceinline__ Rows loadrows(const float* __restrict__ x,
                                         const float* zbuf, int p) {
    Rows r;
    int rem = p & (512*512 - 1);
    int i = rem >> 9, jj = rem & 511;          // jj multiple of 4
    const float* xc = x + p;
    const float* xn = (i > 0)   ? xc - 512 : zbuf;
    const float* xs = (i < 511) ? xc + 512 : zbuf;
    r.C = *(const f4*)xc;
    r.N = *(const f4*)xn;
    r.S = *(const f4*)xs;
    bool hw = (jj > 0), he = (jj < 508);
    float wv  = xc[hw ? -1 : 0];
    float ev  = xc[he ?  4 : 3];
    float nwv = xn[hw ? -1 : 0];
    float sev = xs[he ?  4 : 3];
    r.wv  = hw ? wv  : 0.f;
    r.ev  = he ? ev  : 0.f;
    r.nwv = hw ? nwv : 0.f;
    r.sev = he ? sev : 0.f;
    return r;
}

__device__ __forceinline__ void mkstencil(const Rows& r, f4* s) {
    f4 E   = {r.C.y, r.C.z, r.C.w, r.ev};
    f4 W   = {r.wv,  r.C.x, r.C.y, r.C.z};
    f4 Ssh = {r.S.y, r.S.z, r.S.w, r.sev};
    f4 Nsh = {r.nwv, r.N.x, r.N.y, r.N.z};
    s[0] = r.C;
    s[1] = (r.S - r.N) * 0.5f;
    s[2] = (E - W) * 0.5f;
    s[3] = r.S + r.N - 2.f*r.C;
    s[4] = E + W - 2.f*r.C;
    s[5] = Ssh + Nsh - r.S - E;
}

// ---------------- k_moments: 16 px/thread, packed f2 accumulators ----------------
__global__ __launch_bounds__(256) void k_moments(const float* __restrict__ x,
                                                 float* ws) {
    const float* zbuf = ws + 496;
    int t = threadIdx.x;
    int g0 = blockIdx.x * 1024 + t;
    f2 acc[27];
    #pragma unroll
    for (int i = 0; i < 27; ++i) acc[i] = (f2){0.f, 0.f};

    #pragma unroll
    for (int q = 0; q < 4; ++q) {
        Rows r = loadrows(x, zbuf, (g0 + 256*q) * 4);
        f4 s[6];
        mkstencil(r, s);
        #pragma unroll
        for (int a = 0; a < 6; ++a) {
            f2 alo = s[a].xy, ahi = s[a].zw;
            asm("v_pk_add_f32 %0, %1, %0" : "+v"(acc[a]) : "v"(alo));
            asm("v_pk_add_f32 %0, %1, %0" : "+v"(acc[a]) : "v"(ahi));
            #pragma unroll
            for (int b = a; b < 6; ++b) {
                int idx = 6 + a*(11-a)/2 + b;
                f2 blo = s[b].xy, bhi = s[b].zw;
                asm("v_pk_fma_f32 %0, %1, %2, %0" : "+v"(acc[idx]) : "v"(alo), "v"(blo));
                asm("v_pk_fma_f32 %0, %1, %2, %0" : "+v"(acc[idx]) : "v"(ahi), "v"(bhi));
            }
        }
    }
    __shared__ float red[27][4];
    int wave = t >> 6, lane = t & 63;
    #pragma unroll
    for (int i = 0; i < 27; ++i) {
        float v = acc[i].x + acc[i].y;
        for (int off = 32; off; off >>= 1) v += __shfl_xor(v, off);
        if (lane == 0) red[i][wave] = v;
    }
    __syncthreads();
    if (t < 27) atomicAdd(&ws[t], red[t][0] + red[t][1] + red[t][2] + red[t][3]);
}

// ------------- k_stats1: BN1 fold + A-fragment + w2pad build (64 threads) -------------
__global__ void k_stats1(const float* w1, const float* b1, const float* g1,
                         const float* beta1, const float* w2, float* ws) {
    __shared__ float sm[32][8];
    int c = threadIdx.x;                       // 0..63
    if (c < 32) {
        #pragma unroll
        for (int k = 0; k < 8; ++k) sm[c][k] = 0.f;
        ws[64 + c] = (c < 25) ? w2[c] : 0.f;   // w2pad
    }
    __syncthreads();
    if (c < 25) {
        const float invN = 1.f / (float)NPIX;
        float m1[6], wr[6];
        #pragma unroll
        for (int i = 0; i < 6; ++i) m1[i] = ws[i] * invN;
        #pragma unroll
        for (int i = 0; i < 6; ++i) wr[i] = w1[c*6 + i];
        float bc = b1[c];
        float mean = bc;
        #pragma unroll
        for (int i = 0; i < 6; ++i) mean = fmaf(wr[i], m1[i], mean);
        float e2 = bc * bc;
        #pragma unroll
        for (int i = 0; i < 6; ++i) e2 = fmaf(2.f*bc*wr[i], m1[i], e2);
        #pragma unroll
        for (int i = 0; i < 6; ++i)
            #pragma unroll
            for (int j = 0; j < 6; ++j) {
                int a = i < j ? i : j, b = i < j ? j : i;
                float m2 = ws[6 + a*(11-a)/2 + b] * invN;
                e2 = fmaf(wr[i]*wr[j], m2, e2);
            }
        float var = e2 - mean*mean;
        float a1 = g1[c] * rsqrtf(var + BN_EPS);
        #pragma unroll
        for (int i = 0; i < 6; ++i) sm[c][i] = a1 * wr[i];
        sm[c][6] = fmaf(a1, bc - mean, beta1[c]);   // beff
    }
    __syncthreads();
    // lane c of k_main's waves: ch = c&31, half = c>>5
    int ch = c & 31, h = c >> 5;
    float v0, v1, v2, v3;
    if (h == 0) { v0 = sm[ch][0]; v1 = sm[ch][1]; v2 = sm[ch][2]; v3 = sm[ch][6]; }
    else        { v0 = sm[ch][3]; v1 = sm[ch][4]; v2 = sm[ch][5]; v3 = 0.f; }
    __half2 p0 = __floats2half2_rn(v0, v1);
    __half2 p1 = __floats2half2_rn(v2, v3);
    unsigned u0, u1;
    __builtin_memcpy(&u0, &p0, 4);
    __builtin_memcpy(&u1, &p1, 4);
    uint4 fr = {u0, u1, 0u, 0u};
    ((uint4*)(ws + 96))[c] = fr;
}

// ---------------- k_main: MFMA conv (1 mfma per 32 px per wave) ----------------
__global__ __launch_bounds__(256) void k_main(const float* __restrict__ x,
                                              const float* __restrict__ ws,
                                              const float* __restrict__ b2,
                                              float* __restrict__ stats,
                                              float* __restrict__ opre) {
    int t = threadIdx.x;
    int l = t & 63, wv = t >> 6;
    int lane31 = l & 31, h = l >> 5;
    const float* zb = ws + 496;

    // A fragment: 16B per lane, loop-invariant
    f16x8 afr;
    {
        uint4 u = ((const uint4*)(ws + 96))[l];
        union { uint4 u; f16x8 v; } cv; cv.u = u; afr = cv.v;
    }
    // per-lane w2 column for each accumulator reg: row = (r&3)+8*(r>>2)+4*h
    float w2v[16];
    #pragma unroll
    for (int r = 0; r < 16; ++r) {
        int creg = (r & 3) + 8 * (r >> 2);
        w2v[r] = ws[64 + creg + 4*h];
    }
    f32x16 zacc;
    #pragma unroll
    for (int r = 0; r < 16; ++r) zacc[r] = 0.f;
    float b2v = b2[0];
    float S1 = 0.f, S2 = 0.f;

    int tile0 = (blockIdx.x * 4 + wv) * 32;
    #pragma unroll 1
    for (int it = 0; it < 32; ++it) {
        int tile = tile0 + it;
        int p = tile * 32 + lane31;
        int rem = p & (512*512 - 1);
        int i = rem >> 9, j = rem & 511;
        const float* xc = x + p;
        const float* xn  = (i > 0)   ? xc - 512 : zb;
        const float* xs  = (i < 511) ? xc + 512 : zb;
        const float* xw  = (j > 0)   ? xc - 1   : zb;
        const float* xe  = (j < 511) ? xc + 1   : zb;
        const float* xnw = (j > 0)   ? xn - 1   : zb;
        const float* xse = (j < 511) ? xs + 1   : zb;
        float C = *xc, N = *xn, S_ = *xs, W_ = *xw, E = *xe, NW = *xnw, SE = *xse;

        float v0, v1, v2, v3;
        if (h == 0) { v0 = C;               v1 = (S_ - N) * 0.5f;  v2 = (E - W_) * 0.5f;      v3 = 1.f; }
        else        { v0 = S_ + N - 2.f*C;  v1 = E + W_ - 2.f*C;   v2 = SE + NW - S_ - E;     v3 = 0.f; }
        __half2 p0 = __floats2half2_rn(v0, v1);
        __half2 p1 = __floats2half2_rn(v2, v3);
        unsigned u0, u1;
        __builtin_memcpy(&u0, &p0, 4);
        __builtin_memcpy(&u1, &p1, 4);
        union { uint4 u; f16x8 v; } bv;
        bv.u = (uint4){u0, u1, 0u, 0u};

        f32x16 acc = __builtin_amdgcn_mfma_f32_32x32x16_f16(afr, bv.v, zacc, 0, 0, 0);

        float o = 0.f;
        #pragma unroll
        for (int r = 0; r < 16; ++r)
            o = fmaf(fmaxf(acc[r], 0.f), w2v[r], o);
        o += __shfl_xor(o, 32);      // combine the two channel halves
        o += b2v;
        S1 += o;
        S2 = fmaf(o, o, S2);
        if (l < 32) opre[p] = o;
    }

    for (int off = 32; off; off >>= 1) { S1 += __shfl_xor(S1, off); S2 += __shfl_xor(S2, off); }
    __shared__ float red[2][4];
    if (l == 0) { red[0][wv] = S1; red[1][wv] = S2; }
    __syncthreads();
    // every pixel was counted twice (both lane halves) -> scale 0.5
    if (t == 0) atomicAdd(&stats[27], 0.5f*(red[0][0]+red[0][1]+red[0][2]+red[0][3]));
    if (t == 1) atomicAdd(&stats[28], 0.5f*(red[1][0]+red[1][1]+red[1][2]+red[1][3]));
}

// ---------------- k_final: BN2 fold computed inline ----------------
__global__ __launch_bounds__(256) void k_final(const float* __restrict__ x,
                                               const float* __restrict__ ws,
                                               const float* __restrict__ g2,
                                               const float* __restrict__ beta2,
                                               float* __restrict__ out) {
    const float invN = 1.f / (float)NPIX;
    float mean = ws[27] * invN;
    float var  = ws[28] * invN - mean*mean;
    float a2 = g2[0] * rsqrtf(var + BN_EPS);
    float c2 = fmaf(-mean, a2, beta2[0]);

    int idx = blockIdx.x * 256 + threadIdx.x;  // f4 index, 8192 blocks
    f4 o  = ((const f4*)out)[idx];
    f4 xv = ((const f4*)x)[idx];
    f4 r;
    r.x = fmaxf(fmaf(a2, o.x, c2), 0.f) + xv.x;
    r.y = fmaxf(fmaf(a2, o.y, c2), 0.f) + xv.y;
    r.z = fmaxf(fmaf(a2, o.z, c2), 0.f) + xv.z;
    r.w = fmaxf(fmaf(a2, o.w, c2), 0.f) + xv.w;
    ((f4*)out)[idx] = r;
}

extern "C" void kernel_launch(void* const* d_in, const int* in_sizes, int n_in,
                              void* d_out, int out_size, void* d_ws, size_t ws_size,
                              hipStream_t stream) {
    const float* x     = (const float*)d_in[0];
    const float* w1    = (const float*)d_in[1];
    const float* b1    = (const float*)d_in[2];
    const float* g1    = (const float*)d_in[3];
    const float* beta1 = (const float*)d_in[4];
    const float* w2    = (const float*)d_in[5];
    const float* b2    = (const float*)d_in[6];
    const float* g2    = (const float*)d_in[7];
    const float* beta2 = (const float*)d_in[8];
    float* out = (float*)d_out;
    float* ws  = (float*)d_ws;

    hipMemsetAsync(ws, 0, 2048, stream);
    k_moments<<<2048, 256, 0, stream>>>(x, ws);
    k_stats1 <<<1, 64, 0, stream>>>(w1, b1, g1, beta1, w2, ws);
    k_main   <<<2048, 256, 0, stream>>>(x, ws, b2, ws, out);
    k_final  <<<8192, 256, 0, stream>>>(x, ws, g2, beta2, out);
}

// Round 16
// 125.760 us; speedup vs baseline: 1.1447x; 1.0722x over previous
//
#include <hip/hip_runtime.h>
#include <hip/hip_fp16.h>

typedef float f4 __attribute__((ext_vector_type(4)));
typedef float f2 __attribute__((ext_vector_type(2)));
typedef _Float16 f16x8 __attribute__((ext_vector_type(8)));
typedef float f32x16 __attribute__((ext_vector_type(16)));

#define NPIX (32*512*512)        // 8388608
#define BN_EPS 1e-5f

// ws float layout (memset clears first 8192 bytes = floats 0..2047):
// [0..26]   M1/M2 moment sums
// [27] S1, [28] S2
// [64..95]  w2pad[32] (zero-padded w2)
// [96..352) A-fragment per lane: 64 x 4 uints (f16x8 bit patterns)
// [496]     zbuf for k_moments (reads floats 495..500)
// [1024]    zbuf for k_main rows (reads floats 1023..1537)

struct Rows { f4 C, N, S; float wv, ev, nwv, sev; };

__device__ __forceinline__ Rows loadrows(const float* __restrict__ x,
                                         const float* zbuf, int p) {
    Rows r;
    int rem = p & (512*512 - 1);
    int i = rem >> 9, jj = rem & 511;          // jj multiple of 4
    const float* xc = x + p;
    const float* xn = (i > 0)   ? xc - 512 : zbuf;
    const float* xs = (i < 511) ? xc + 512 : zbuf;
    r.C = *(const f4*)xc;
    r.N = *(const f4*)xn;
    r.S = *(const f4*)xs;
    bool hw = (jj > 0), he = (jj < 508);
    float wv  = xc[hw ? -1 : 0];
    float ev  = xc[he ?  4 : 3];
    float nwv = xn[hw ? -1 : 0];
    float sev = xs[he ?  4 : 3];
    r.wv  = hw ? wv  : 0.f;
    r.ev  = he ? ev  : 0.f;
    r.nwv = hw ? nwv : 0.f;
    r.sev = he ? sev : 0.f;
    return r;
}

__device__ __forceinline__ void mkstencil(const Rows& r, f4* s) {
    f4 E   = {r.C.y, r.C.z, r.C.w, r.ev};
    f4 W   = {r.wv,  r.C.x, r.C.y, r.C.z};
    f4 Ssh = {r.S.y, r.S.z, r.S.w, r.sev};
    f4 Nsh = {r.nwv, r.N.x, r.N.y, r.N.z};
    s[0] = r.C;
    s[1] = (r.S - r.N) * 0.5f;
    s[2] = (E - W) * 0.5f;
    s[3] = r.S + r.N - 2.f*r.C;
    s[4] = E + W - 2.f*r.C;
    s[5] = Ssh + Nsh - r.S - E;
}

// ---------------- k_moments: 16 px/thread, packed f2 accumulators ----------------
__global__ __launch_bounds__(256) void k_moments(const float* __restrict__ x,
                                                 float* ws) {
    const float* zbuf = ws + 496;
    int t = threadIdx.x;
    int g0 = blockIdx.x * 1024 + t;
    f2 acc[27];
    #pragma unroll
    for (int i = 0; i < 27; ++i) acc[i] = (f2){0.f, 0.f};

    #pragma unroll
    for (int q = 0; q < 4; ++q) {
        Rows r = loadrows(x, zbuf, (g0 + 256*q) * 4);
        f4 s[6];
        mkstencil(r, s);
        #pragma unroll
        for (int a = 0; a < 6; ++a) {
            f2 alo = s[a].xy, ahi = s[a].zw;
            asm("v_pk_add_f32 %0, %1, %0" : "+v"(acc[a]) : "v"(alo));
            asm("v_pk_add_f32 %0, %1, %0" : "+v"(acc[a]) : "v"(ahi));
            #pragma unroll
            for (int b = a; b < 6; ++b) {
                int idx = 6 + a*(11-a)/2 + b;
                f2 blo = s[b].xy, bhi = s[b].zw;
                asm("v_pk_fma_f32 %0, %1, %2, %0" : "+v"(acc[idx]) : "v"(alo), "v"(blo));
                asm("v_pk_fma_f32 %0, %1, %2, %0" : "+v"(acc[idx]) : "v"(ahi), "v"(bhi));
            }
        }
    }
    __shared__ float red[27][4];
    int wave = t >> 6, lane = t & 63;
    #pragma unroll
    for (int i = 0; i < 27; ++i) {
        float v = acc[i].x + acc[i].y;
        for (int off = 32; off; off >>= 1) v += __shfl_xor(v, off);
        if (lane == 0) red[i][wave] = v;
    }
    __syncthreads();
    if (t < 27) atomicAdd(&ws[t], red[t][0] + red[t][1] + red[t][2] + red[t][3]);
}

// ------------- k_stats1: BN1 fold + A-fragment + w2pad build (64 threads) -------------
__global__ void k_stats1(const float* w1, const float* b1, const float* g1,
                         const float* beta1, const float* w2, float* ws) {
    __shared__ float sm[32][8];
    int c = threadIdx.x;                       // 0..63
    if (c < 32) {
        #pragma unroll
        for (int k = 0; k < 8; ++k) sm[c][k] = 0.f;
        ws[64 + c] = (c < 25) ? w2[c] : 0.f;   // w2pad
    }
    __syncthreads();
    if (c < 25) {
        const float invN = 1.f / (float)NPIX;
        float m1[6], wr[6];
        #pragma unroll
        for (int i = 0; i < 6; ++i) m1[i] = ws[i] * invN;
        #pragma unroll
        for (int i = 0; i < 6; ++i) wr[i] = w1[c*6 + i];
        float bc = b1[c];
        float mean = bc;
        #pragma unroll
        for (int i = 0; i < 6; ++i) mean = fmaf(wr[i], m1[i], mean);
        float e2 = bc * bc;
        #pragma unroll
        for (int i = 0; i < 6; ++i) e2 = fmaf(2.f*bc*wr[i], m1[i], e2);
        #pragma unroll
        for (int i = 0; i < 6; ++i)
            #pragma unroll
            for (int j = 0; j < 6; ++j) {
                int a = i < j ? i : j, b = i < j ? j : i;
                float m2 = ws[6 + a*(11-a)/2 + b] * invN;
                e2 = fmaf(wr[i]*wr[j], m2, e2);
            }
        float var = e2 - mean*mean;
        float a1 = g1[c] * rsqrtf(var + BN_EPS);
        #pragma unroll
        for (int i = 0; i < 6; ++i) sm[c][i] = a1 * wr[i];
        sm[c][6] = fmaf(a1, bc - mean, beta1[c]);   // beff
    }
    __syncthreads();
    int ch = c & 31, h = c >> 5;
    float v0, v1, v2, v3;
    if (h == 0) { v0 = sm[ch][0]; v1 = sm[ch][1]; v2 = sm[ch][2]; v3 = sm[ch][6]; }
    else        { v0 = sm[ch][3]; v1 = sm[ch][4]; v2 = sm[ch][5]; v3 = 0.f; }
    __half2 p0 = __floats2half2_rn(v0, v1);
    __half2 p1 = __floats2half2_rn(v2, v3);
    unsigned u0, u1;
    __builtin_memcpy(&u0, &p0, 4);
    __builtin_memcpy(&u1, &p1, 4);
    uint4 fr = {u0, u1, 0u, 0u};
    ((uint4*)(ws + 96))[c] = fr;
}

// ------- k_main: MFMA conv, row-structured, immediate-offset loads -------
__global__ __launch_bounds__(256) void k_main(const float* __restrict__ x,
                                              const float* __restrict__ ws,
                                              const float* __restrict__ b2,
                                              float* __restrict__ stats,
                                              float* __restrict__ opre) {
    int t = threadIdx.x;
    int l = t & 63, wv = t >> 6;
    int lane31 = l & 31, h = l >> 5;
    const float* zb = ws + 1024;

    // A fragment: 16B per lane, loop-invariant
    f16x8 afr;
    {
        uint4 u = ((const uint4*)(ws + 96))[l];
        union { uint4 u; f16x8 v; } cv; cv.u = u; afr = cv.v;
    }
    // per-lane w2 for each accumulator reg: channel = (r&3)+8*(r>>2)+4*h
    float w2v[16];
    #pragma unroll
    for (int r = 0; r < 16; ++r) {
        int creg = (r & 3) + 8 * (r >> 2);
        w2v[r] = ws[64 + creg + 4*h];
    }
    f32x16 zacc;
    #pragma unroll
    for (int r = 0; r < 16; ++r) zacc[r] = 0.f;
    float b2v = b2[0];
    float v3 = h ? 0.f : 1.f;                 // bias k-slot, loop-invariant
    float S1 = 0.f, S2 = 0.f;

    int wave_id = blockIdx.x * 4 + wv;        // 8192 waves x 2 rows = 16384 rows
    #pragma unroll 1
    for (int rr = 0; rr < 2; ++rr) {
        int row = wave_id * 2 + rr;           // global row (batch*512 + i)
        int i = row & 511;
        const float* xc = x + row * 512 + lane31;
        const float* xn = (i > 0)   ? xc - 512 : zb + lane31;
        const float* xs = (i < 511) ? xc + 512 : zb + lane31;
        float* op = opre + row * 512 + lane31;

        #pragma unroll
        for (int jt = 0; jt < 16; ++jt) {
            const int o4 = jt * 32;
            // edge tiles: clamp offset BEFORE the load (OOB-safe), then mask value
            int offm1 = o4 - 1, offp1 = o4 + 1;
            if (jt == 0  && lane31 == 0)  offm1 = o4;
            if (jt == 15 && lane31 == 31) offp1 = o4;

            float C  = xc[o4];
            float W_ = xc[offm1];
            float E  = xc[offp1];
            float N  = xn[o4];
            float NW = xn[offm1];
            float S_ = xs[o4];
            float SE = xs[offp1];
            if (jt == 0)  { bool ok = (lane31 != 0);  W_ = ok ? W_ : 0.f; NW = ok ? NW : 0.f; }
            if (jt == 15) { bool ok = (lane31 != 31); E  = ok ? E  : 0.f; SE = ok ? SE : 0.f; }

            float a0 = S_ + N - 2.f*C;
            float a1 = E + W_ - 2.f*C;
            float a2 = SE + NW - S_ - E;
            float v0 = h ? a0 : C;
            float v1 = h ? a1 : (S_ - N) * 0.5f;
            float v2 = h ? a2 : (E - W_) * 0.5f;

            __half2 p0 = __floats2half2_rn(v0, v1);
            __half2 p1 = __floats2half2_rn(v2, v3);
            unsigned u0, u1;
            __builtin_memcpy(&u0, &p0, 4);
            __builtin_memcpy(&u1, &p1, 4);
            union { uint4 u; f16x8 v; } bv;
            bv.u = (uint4){u0, u1, 0u, 0u};

            f32x16 acc = __builtin_amdgcn_mfma_f32_32x32x16_f16(afr, bv.v, zacc, 0, 0, 0);

            float o = 0.f;
            #pragma unroll
            for (int r = 0; r < 16; ++r)
                o = fmaf(fmaxf(acc[r], 0.f), w2v[r], o);
            o += __shfl_xor(o, 32);           // combine the two channel halves
            o += b2v;
            S1 += o;
            S2 = fmaf(o, o, S2);
            if (l < 32) op[o4] = o;
        }
    }

    for (int off = 32; off; off >>= 1) { S1 += __shfl_xor(S1, off); S2 += __shfl_xor(S2, off); }
    __shared__ float red[2][4];
    if (l == 0) { red[0][wv] = S1; red[1][wv] = S2; }
    __syncthreads();
    // every pixel counted by both lane halves -> scale 0.5
    if (t == 0) atomicAdd(&stats[27], 0.5f*(red[0][0]+red[0][1]+red[0][2]+red[0][3]));
    if (t == 1) atomicAdd(&stats[28], 0.5f*(red[1][0]+red[1][1]+red[1][2]+red[1][3]));
}

// ---------------- k_final: BN2 fold computed inline ----------------
__global__ __launch_bounds__(256) void k_final(const float* __restrict__ x,
                                               const float* __restrict__ ws,
                                               const float* __restrict__ g2,
                                               const float* __restrict__ beta2,
                                               float* __restrict__ out) {
    const float invN = 1.f / (float)NPIX;
    float mean = ws[27] * invN;
    float var  = ws[28] * invN - mean*mean;
    float a2 = g2[0] * rsqrtf(var + BN_EPS);
    float c2 = fmaf(-mean, a2, beta2[0]);

    int idx = blockIdx.x * 256 + threadIdx.x;  // f4 index, 8192 blocks
    f4 o  = ((const f4*)out)[idx];
    f4 xv = ((const f4*)x)[idx];
    f4 r;
    r.x = fmaxf(fmaf(a2, o.x, c2), 0.f) + xv.x;
    r.y = fmaxf(fmaf(a2, o.y, c2), 0.f) + xv.y;
    r.z = fmaxf(fmaf(a2, o.z, c2), 0.f) + xv.z;
    r.w = fmaxf(fmaf(a2, o.w, c2), 0.f) + xv.w;
    ((f4*)out)[idx] = r;
}

extern "C" void kernel_launch(void* const* d_in, const int* in_sizes, int n_in,
                              void* d_out, int out_size, void* d_ws, size_t ws_size,
                              hipStream_t stream) {
    const float* x     = (const float*)d_in[0];
    const float* w1    = (const float*)d_in[1];
    const float* b1    = (const float*)d_in[2];
    const float* g1    = (const float*)d_in[3];
    const float* beta1 = (const float*)d_in[4];
    const float* w2    = (const float*)d_in[5];
    const float* b2    = (const float*)d_in[6];
    const float* g2    = (const float*)d_in[7];
    const float* beta2 = (const float*)d_in[8];
    float* out = (float*)d_out;
    float* ws  = (float*)d_ws;

    hipMemsetAsync(ws, 0, 8192, stream);
    k_moments<<<2048, 256, 0, stream>>>(x, ws);
    k_stats1 <<<1, 64, 0, stream>>>(w1, b1, g1, beta1, w2, ws);
    k_main   <<<2048, 256, 0, stream>>>(x, ws, b2, ws, out);
    k_final  <<<8192, 256, 0, stream>>>(x, ws, g2, beta2, out);
}

// Round 17
// 100.155 us; speedup vs baseline: 1.4374x; 1.2556x over previous
//
#include <hip/hip_runtime.h>
#include <hip/hip_fp16.h>

typedef float f4 __attribute__((ext_vector_type(4)));
typedef float f2 __attribute__((ext_vector_type(2)));
typedef _Float16 f16x8 __attribute__((ext_vector_type(8)));
typedef float f32x16 __attribute__((ext_vector_type(16)));

#define NPIX (32*512*512)        // 8388608
#define BN_EPS 1e-5f

// ws float layout (memset clears first 8192 bytes = floats 0..2047):
// [0..26]   reduced M1/M2 moment sums (written by k_red)
// [27] S1, [28] S2 (written by k_redS)
// [64..95]  w2pad[32]
// [96..352) A'-fragment per lane: 64 x uint4 (f16x8 bit patterns)
// [496]     zbuf for k_moments (reads floats 495..500)
// [1024]    zbuf for k_main rows (reads floats 1023..1537)
// [4096..6144)  S1 partials [bid], S2 partials at [6144..8192)... (see below)
// NOTE: S partials live at ws[2048+bid] (S1) and ws[4096+bid] (S2); only
//       floats 0..2047 are memset (partials are fully overwritten each launch).
// k_moments block partials live in d_out[i*2048 + bid] (overwritten by opre later).

struct Rows { f4 C, N, S; float wv, ev, nwv, sev; };

__device__ __forceinline__ Rows loadrows(const float* __restrict__ x,
                                         const float* zbuf, int p) {
    Rows r;
    int rem = p & (512*512 - 1);
    int i = rem >> 9, jj = rem & 511;          // jj multiple of 4
    const float* xc = x + p;
    const float* xn = (i > 0)   ? xc - 512 : zbuf;
    const float* xs = (i < 511) ? xc + 512 : zbuf;
    r.C = *(const f4*)xc;
    r.N = *(const f4*)xn;
    r.S = *(const f4*)xs;
    bool hw = (jj > 0), he = (jj < 508);
    float wv  = xc[hw ? -1 : 0];
    float ev  = xc[he ?  4 : 3];
    float nwv = xn[hw ? -1 : 0];
    float sev = xs[he ?  4 : 3];
    r.wv  = hw ? wv  : 0.f;
    r.ev  = he ? ev  : 0.f;
    r.nwv = hw ? nwv : 0.f;
    r.sev = he ? sev : 0.f;
    return r;
}

__device__ __forceinline__ void mkstencil(const Rows& r, f4* s) {
    f4 E   = {r.C.y, r.C.z, r.C.w, r.ev};
    f4 W   = {r.wv,  r.C.x, r.C.y, r.C.z};
    f4 Ssh = {r.S.y, r.S.z, r.S.w, r.sev};
    f4 Nsh = {r.nwv, r.N.x, r.N.y, r.N.z};
    s[0] = r.C;
    s[1] = (r.S - r.N) * 0.5f;
    s[2] = (E - W) * 0.5f;
    s[3] = r.S + r.N - 2.f*r.C;
    s[4] = E + W - 2.f*r.C;
    s[5] = Ssh + Nsh - r.S - E;
}

// ------- k_moments: 16 px/thread, packed f2 accumulators, partials to d_out -------
__global__ __launch_bounds__(256) void k_moments(const float* __restrict__ x,
                                                 const float* __restrict__ ws,
                                                 float* __restrict__ outp) {
    const float* zbuf = ws + 496;
    int t = threadIdx.x;
    int g0 = blockIdx.x * 1024 + t;
    f2 acc[27];
    #pragma unroll
    for (int i = 0; i < 27; ++i) acc[i] = (f2){0.f, 0.f};

    #pragma unroll
    for (int q = 0; q < 4; ++q) {
        Rows r = loadrows(x, zbuf, (g0 + 256*q) * 4);
        f4 s[6];
        mkstencil(r, s);
        #pragma unroll
        for (int a = 0; a < 6; ++a) {
            f2 alo = s[a].xy, ahi = s[a].zw;
            asm("v_pk_add_f32 %0, %1, %0" : "+v"(acc[a]) : "v"(alo));
            asm("v_pk_add_f32 %0, %1, %0" : "+v"(acc[a]) : "v"(ahi));
            #pragma unroll
            for (int b = a; b < 6; ++b) {
                int idx = 6 + a*(11-a)/2 + b;
                f2 blo = s[b].xy, bhi = s[b].zw;
                asm("v_pk_fma_f32 %0, %1, %2, %0" : "+v"(acc[idx]) : "v"(alo), "v"(blo));
                asm("v_pk_fma_f32 %0, %1, %2, %0" : "+v"(acc[idx]) : "v"(ahi), "v"(bhi));
            }
        }
    }
    __shared__ float red[27][4];
    int wave = t >> 6, lane = t & 63;
    #pragma unroll
    for (int i = 0; i < 27; ++i) {
        float v = acc[i].x + acc[i].y;
        for (int off = 32; off; off >>= 1) v += __shfl_xor(v, off);
        if (lane == 0) red[i][wave] = v;
    }
    __syncthreads();
    if (t < 27)
        outp[t*2048 + blockIdx.x] = red[t][0] + red[t][1] + red[t][2] + red[t][3];
}

// ------- k_red: reduce 27 x 2048 partials from d_out into ws[0..26] -------
__global__ __launch_bounds__(256) void k_red(const float* __restrict__ outp,
                                             float* __restrict__ ws) {
    int b = blockIdx.x;                        // 0..26
    int t = threadIdx.x;
    float v = 0.f;
    #pragma unroll
    for (int k = 0; k < 8; ++k) v += outp[b*2048 + t + 256*k];
    for (int off = 32; off; off >>= 1) v += __shfl_xor(v, off);
    __shared__ float red[4];
    int wave = t >> 6, lane = t & 63;
    if (lane == 0) red[wave] = v;
    __syncthreads();
    if (t == 0) ws[b] = red[0] + red[1] + red[2] + red[3];
}

// ------- k_stats1: BN1 fold -> A' = W1eff*D fragment + w2pad (64 threads) -------
__global__ void k_stats1(const float* w1, const float* b1, const float* g1,
                         const float* beta1, const float* w2, float* ws) {
    __shared__ float sm[32][8];
    int c = threadIdx.x;                       // 0..63
    if (c < 32) {
        #pragma unroll
        for (int k = 0; k < 8; ++k) sm[c][k] = 0.f;
        ws[64 + c] = (c < 25) ? w2[c] : 0.f;   // w2pad
    }
    __syncthreads();
    if (c < 25) {
        const float invN = 1.f / (float)NPIX;
        float m1[6], wr[6];
        #pragma unroll
        for (int i = 0; i < 6; ++i) m1[i] = ws[i] * invN;
        #pragma unroll
        for (int i = 0; i < 6; ++i) wr[i] = w1[c*6 + i];
        float bc = b1[c];
        float mean = bc;
        #pragma unroll
        for (int i = 0; i < 6; ++i) mean = fmaf(wr[i], m1[i], mean);
        float e2 = bc * bc;
        #pragma unroll
        for (int i = 0; i < 6; ++i) e2 = fmaf(2.f*bc*wr[i], m1[i], e2);
        #pragma unroll
        for (int i = 0; i < 6; ++i)
            #pragma unroll
            for (int j = 0; j < 6; ++j) {
                int a = i < j ? i : j, b = i < j ? j : i;
                float m2 = ws[6 + a*(11-a)/2 + b] * invN;
                e2 = fmaf(wr[i]*wr[j], m2, e2);
            }
        float var = e2 - mean*mean;
        float a1 = g1[c] * rsqrtf(var + BN_EPS);
        #pragma unroll
        for (int i = 0; i < 6; ++i) sm[c][i] = a1 * wr[i];
        sm[c][6] = fmaf(a1, bc - mean, beta1[c]);   // beff
    }
    __syncthreads();
    // A' = W1eff * D : coefficients on raw neighbors {C,N,S,E,W,NW,SE,1}
    int ch = c & 31, h = c >> 5;
    float aC=0.f, aN=0.f, aS=0.f, aE=0.f, aW=0.f, aNW=0.f, aSE=0.f, ab=0.f;
    if (h == 0) {
        float w0 = sm[ch][0], w1v = sm[ch][1], w2v = sm[ch][2];
        float w3 = sm[ch][3], w4v = sm[ch][4], w5 = sm[ch][5], be = sm[ch][6];
        aC  = w0 - 2.f*w3 - 2.f*w4v;
        aN  = -0.5f*w1v + w3;
        aS  =  0.5f*w1v + w3 - w5;
        aE  =  0.5f*w2v + w4v - w5;
        aW  = -0.5f*w2v + w4v;
        aNW = w5;
        aSE = w5;
        ab  = be;
    }
    __half2 p0 = __floats2half2_rn(aC,  aN);
    __half2 p1 = __floats2half2_rn(aS,  aE);
    __half2 p2 = __floats2half2_rn(aW,  aNW);
    __half2 p3 = __floats2half2_rn(aSE, ab);
    unsigned u0, u1, u2, u3;
    __builtin_memcpy(&u0, &p0, 4);
    __builtin_memcpy(&u1, &p1, 4);
    __builtin_memcpy(&u2, &p2, 4);
    __builtin_memcpy(&u3, &p3, 4);
    uint4 fr = {u0, u1, u2, u3};
    ((uint4*)(ws + 96))[c] = fr;
}

// ------- k_main: MFMA conv on RAW neighbors (stencil folded into A') -------
__global__ __launch_bounds__(256) void k_main(const float* __restrict__ x,
                                              const float* __restrict__ ws,
                                              const float* __restrict__ b2,
                                              float* __restrict__ stats,
                                              float* __restrict__ opre) {
    int t = threadIdx.x;
    int l = t & 63, wv = t >> 6;
    int lane31 = l & 31, h = l >> 5;
    const float* zb = ws + 1024;

    f16x8 afr;
    {
        uint4 u = ((const uint4*)(ws + 96))[l];
        union { uint4 u; f16x8 v; } cv; cv.u = u; afr = cv.v;
    }
    float w2v[16];
    #pragma unroll
    for (int r = 0; r < 16; ++r) {
        int creg = (r & 3) + 8 * (r >> 2);
        w2v[r] = ws[64 + creg + 4*h];
    }
    f32x16 zacc;
    #pragma unroll
    for (int r = 0; r < 16; ++r) zacc[r] = 0.f;
    float b2v = b2[0];
    float S1 = 0.f, S2 = 0.f;

    int wave_id = blockIdx.x * 4 + wv;        // 8192 waves x 2 rows = 16384 rows
    #pragma unroll 1
    for (int rr = 0; rr < 2; ++rr) {
        int row = wave_id * 2 + rr;
        int i = row & 511;
        const float* xc = x + row * 512 + lane31;
        const float* xn = (i > 0)   ? xc - 512 : zb + lane31;
        const float* xs = (i < 511) ? xc + 512 : zb + lane31;
        float* op = opre + row * 512 + lane31;

        #pragma unroll
        for (int jt = 0; jt < 16; ++jt) {
            const int o4 = jt * 32;
            int offm1 = o4 - 1, offp1 = o4 + 1;
            if (jt == 0  && lane31 == 0)  offm1 = o4;   // OOB-safe clamp
            if (jt == 15 && lane31 == 31) offp1 = o4;

            float C  = xc[o4];
            float W_ = xc[offm1];
            float E  = xc[offp1];
            float N  = xn[o4];
            float NW = xn[offm1];
            float S_ = xs[o4];
            float SE = xs[offp1];
            if (jt == 0)  { bool ok = (lane31 != 0);  W_ = ok ? W_ : 0.f; NW = ok ? NW : 0.f; }
            if (jt == 15) { bool ok = (lane31 != 31); E  = ok ? E  : 0.f; SE = ok ? SE : 0.f; }

            // B fragment = raw neighbors {C,N},{S,E},{W,NW},{SE,1}
            // (h=1 half is don't-care: its A' half is zero)
            __half2 p0 = __floats2half2_rn(C,  N);
            __half2 p1 = __floats2half2_rn(S_, E);
            __half2 p2 = __floats2half2_rn(W_, NW);
            __half2 p3 = __floats2half2_rn(SE, 1.f);
            unsigned u0, u1, u2, u3;
            __builtin_memcpy(&u0, &p0, 4);
            __builtin_memcpy(&u1, &p1, 4);
            __builtin_memcpy(&u2, &p2, 4);
            __builtin_memcpy(&u3, &p3, 4);
            union { uint4 u; f16x8 v; } bv;
            bv.u = (uint4){u0, u1, u2, u3};

            f32x16 acc = __builtin_amdgcn_mfma_f32_32x32x16_f16(afr, bv.v, zacc, 0, 0, 0);

            float o = 0.f;
            #pragma unroll
            for (int r = 0; r < 16; ++r)
                o = fmaf(fmaxf(acc[r], 0.f), w2v[r], o);
            o += __shfl_xor(o, 32);           // combine the two channel halves
            o += b2v;
            S1 += o;
            S2 = fmaf(o, o, S2);
            if (l < 32) op[o4] = o;
        }
    }

    for (int off = 32; off; off >>= 1) { S1 += __shfl_xor(S1, off); S2 += __shfl_xor(S2, off); }
    __shared__ float red[2][4];
    if (l == 0) { red[0][wv] = S1; red[1][wv] = S2; }
    __syncthreads();
    // every pixel counted by both lane halves -> scale 0.5; plain stores (no atomics)
    if (t == 0) stats[2048 + blockIdx.x] = 0.5f*(red[0][0]+red[0][1]+red[0][2]+red[0][3]);
    if (t == 1) stats[4096 + blockIdx.x] = 0.5f*(red[1][0]+red[1][1]+red[1][2]+red[1][3]);
}

// ------- k_redS: reduce S1/S2 partials into ws[27], ws[28] -------
__global__ __launch_bounds__(256) void k_redS(float* __restrict__ ws) {
    int t = threadIdx.x;
    float s1 = 0.f, s2 = 0.f;
    #pragma unroll
    for (int k = 0; k < 8; ++k) {
        s1 += ws[2048 + t + 256*k];
        s2 += ws[4096 + t + 256*k];
    }
    for (int off = 32; off; off >>= 1) { s1 += __shfl_xor(s1, off); s2 += __shfl_xor(s2, off); }
    __shared__ float red[2][4];
    int wave = t >> 6, lane = t & 63;
    if (lane == 0) { red[0][wave] = s1; red[1][wave] = s2; }
    __syncthreads();
    if (t == 0) ws[27] = red[0][0] + red[0][1] + red[0][2] + red[0][3];
    if (t == 1) ws[28] = red[1][0] + red[1][1] + red[1][2] + red[1][3];
}

// ---------------- k_final: BN2 fold computed inline ----------------
__global__ __launch_bounds__(256) void k_final(const float* __restrict__ x,
                                               const float* __restrict__ ws,
                                               const float* __restrict__ g2,
                                               const float* __restrict__ beta2,
                                               float* __restrict__ out) {
    const float invN = 1.f / (float)NPIX;
    float mean = ws[27] * invN;
    float var  = ws[28] * invN - mean*mean;
    float a2 = g2[0] * rsqrtf(var + BN_EPS);
    float c2 = fmaf(-mean, a2, beta2[0]);

    int idx = blockIdx.x * 256 + threadIdx.x;  // f4 index, 8192 blocks
    f4 o  = ((const f4*)out)[idx];
    f4 xv = ((const f4*)x)[idx];
    f4 r;
    r.x = fmaxf(fmaf(a2, o.x, c2), 0.f) + xv.x;
    r.y = fmaxf(fmaf(a2, o.y, c2), 0.f) + xv.y;
    r.z = fmaxf(fmaf(a2, o.z, c2), 0.f) + xv.z;
    r.w = fmaxf(fmaf(a2, o.w, c2), 0.f) + xv.w;
    ((f4*)out)[idx] = r;
}

extern "C" void kernel_launch(void* const* d_in, const int* in_sizes, int n_in,
                              void* d_out, int out_size, void* d_ws, size_t ws_size,
                              hipStream_t stream) {
    const float* x     = (const float*)d_in[0];
    const float* w1    = (const float*)d_in[1];
    const float* b1    = (const float*)d_in[2];
    const float* g1    = (const float*)d_in[3];
    const float* beta1 = (const float*)d_in[4];
    const float* w2    = (const float*)d_in[5];
    const float* b2    = (const float*)d_in[6];
    const float* g2    = (const float*)d_in[7];
    const float* beta2 = (const float*)d_in[8];
    float* out = (float*)d_out;
    float* ws  = (float*)d_ws;

    hipMemsetAsync(ws, 0, 8192, stream);
    k_moments<<<2048, 256, 0, stream>>>(x, ws, out);
    k_red    <<<27, 256, 0, stream>>>(out, ws);
    k_stats1 <<<1, 64, 0, stream>>>(w1, b1, g1, beta1, w2, ws);
    k_main   <<<2048, 256, 0, stream>>>(x, ws, b2, ws, out);
    k_redS   <<<1, 256, 0, stream>>>(ws);
    k_final  <<<8192, 256, 0, stream>>>(x, ws, g2, beta2, out);
}